// Round 11
// baseline (90.005 us; speedup 1.0000x reference)
//
#include <hip/hip_runtime.h>
#include <hip/hip_bf16.h>
#include <cstdint>

// m=8, n=4096, dx=2, dz=16, grid 64x64 -> M=4096. All I/O fp32.
// R11 = R8 barrier-free MFMA K-loop, launch_bounds relaxed (512,4) so the
// ~48-live-value loop fits in 128 VGPRs with NO scratch spills (the (512,6)
// 85-VGPR cap forced spilling - removed as a container-wedge suspect).
// Per block (gtile,b): z_grid[64][16] = W[64 x C] * Z[C x 16] via
// mfma_f32_16x16x32_bf16.
//  - Phase A: compact survivors into ONE uint2 record each:
//      (e0 = q0*(g0-x0)^2 as fp32,  bf16(x1)<<16 | n).   32 KB LDS.
//  - K-loop: NO __syncthreads, NO staging. Lane L owns B[k=(L>>4)*8+j][n=L&15]
//    -> per j a quarter-wave reads one contiguous 64-B z row (coalesced).
//    A-frag weights computed from the same records (A k-map == B k-map,
//    HW-verified m89/m120). One MFMA per wave per 64 survivors
//    (ks = w>>2 splits K, mt = w&3 picks the 16-col M-tile).
//  - Pairwise wave reduction (w, w+4) through LDS (aliases dead records).
#define N_PTS   4096
#define M_GRID  4096
#define SKIP_E0 -20.0f              // exp(-20)=2e-9; skip error < 4e-5

typedef __attribute__((ext_vector_type(8))) short  short8;   // 8 bf16
typedef __attribute__((ext_vector_type(4))) float  floatx4;

// LDS: rec uint2[4096] = 32768 B; cnt 4 B; red (post-loop) aliases rec.
#define SMEM_BYTES 32772

__device__ __forceinline__ float bits_hi_f(uint32_t u) {
    union { uint32_t u; float f; } c; c.u = u & 0xffff0000u; return c.f;
}
__device__ __forceinline__ float bits_f(uint32_t u) {
    union { uint32_t u; float f; } c; c.u = u; return c.f;
}
__device__ __forceinline__ uint32_t pack_bf2(float a, float b) {
    union { __hip_bfloat162 h; uint32_t u; } c;
    c.h = __float22bfloat162_rn(make_float2(a, b));
    return c.u;
}

__global__ __launch_bounds__(512, 4)
void setconv_kernel(const float2* __restrict__ x2,     // [8*4096]
                    const float*  __restrict__ zf,     // [8*4096*16]
                    const float*  __restrict__ lsp,    // [2]
                    const float2* __restrict__ grid2,  // [4096]
                    float2*       __restrict__ outx,   // x_grid [8*4096]
                    float*        __restrict__ outz)   // z_grid [8*4096*16]
{
    __shared__ __align__(16) char smem[SMEM_BYTES];
    uint2*   rec  = reinterpret_cast<uint2*>(smem);       // survivor records
    floatx4* redv = reinterpret_cast<floatx4*>(smem);     // aliases rec (late)
    int*     cntp = reinterpret_cast<int*>(smem + 32768);

    const int tid  = threadIdx.x;
    const int lane = tid & 63;
    const int w    = tid >> 6;          // wave 0..7
    const int mt   = w & 3;             // M-tile (grid cols mt*16..+15)
    const int ks   = w >> 2;            // K-slab half (0/1)
    const int q    = lane >> 4;         // quarter within wave
    const int dn   = lane & 15;         // dz index (B) == m within tile (A/D)
    const int gtile = blockIdx.x;       // 0..63 (grid row; g0 block-uniform)
    const int b     = blockIdx.y;       // 0..7

    // lengthscale = 1e-5 + softplus(param)
    float p0 = lsp[0], p1 = lsp[1];
    float sp0 = (p0 > 0.f) ? (p0 + log1pf(expf(-p0))) : log1pf(expf(p0));
    float sp1 = (p1 > 0.f) ? (p1 + log1pf(expf(-p1))) : log1pf(expf(p1));
    float ls0 = 1e-5f + sp0, ls1 = 1e-5f + sp1;
    const float q0 = -0.5f / (ls0 * ls0);   // wgt = exp(q0*d0^2 + q1*d1^2)
    const float q1 = -0.5f / (ls1 * ls1);

    const float2 gv = grid2[gtile * 64 + lane];
    const float  g0 = gv.x;                 // block-uniform row coord
    if (w == 0) outx[(size_t)b * M_GRID + gtile * 64 + lane] = gv;
    // col coord of this lane's A/D row (m = dn within M-tile mt)
    const float g1m = grid2[gtile * 64 + mt * 16 + dn].y;

    if (tid == 0) *cntp = 0;
    __syncthreads();

    const float2* xb = x2 + b * N_PTS;

    // ---- Phase A: compact survivors into packed records ----
    for (int t = tid; t < N_PTS; t += 512) {
        float2 xv = xb[t];
        float d0 = g0 - xv.x;
        float e0 = q0 * d0 * d0;
        bool keep = (e0 >= SKIP_E0);
        unsigned long long m = __ballot(keep);
        int base = 0;
        if (lane == 0 && m) base = atomicAdd(cntp, __popcll(m));
        base = __shfl(base, 0);
        if (keep) {
            int off = __popcll(m & ((1ull << lane) - 1ull));
            __hip_bfloat16 hx = __float2bfloat16(xv.y);
            uint32_t x1n = ((uint32_t)*reinterpret_cast<uint16_t*>(&hx) << 16)
                         | (uint32_t)t;
            union { float f; uint32_t u; } ee; ee.f = e0;
            rec[base + off] = make_uint2(ee.u, x1n);
        }
    }
    __syncthreads();
    const int C    = *cntp;
    const int Cpad = (C + 63) & ~63;
    for (int t = C + tid; t < Cpad; t += 512) {   // sentinel: wgt -> 0, n=0
        union { float f; uint32_t u; } ee; ee.f = -1e30f;
        rec[t] = make_uint2(ee.u, 0u);
    }
    __syncthreads();

    const int ngroup = Cpad >> 6;       // 64 survivors per group (2 K-slabs)
    // this lane's z column: row n -> zcol[n*16]
    const float* zcol = zf + (size_t)b * (N_PTS * 16) + dn;

    floatx4 acc = {0.f, 0.f, 0.f, 0.f};

    for (int gi = 0; gi < ngroup; ++gi) {
        const int k0 = (gi << 6) + (ks << 5) + (q << 3);
        const uint4* rq = reinterpret_cast<const uint4*>(rec + k0);
        uint4 r0 = rq[0], r1 = rq[1], r2 = rq[2], r3 = rq[3];  // 8 records

        // B: 8 independent coalesced dword loads (quarter-wave = one 64-B row)
        float z0 = zcol[(size_t)(r0.y & 0xffffu) * 16];
        float z1 = zcol[(size_t)(r0.w & 0xffffu) * 16];
        float z2 = zcol[(size_t)(r1.y & 0xffffu) * 16];
        float z3 = zcol[(size_t)(r1.w & 0xffffu) * 16];
        float z4 = zcol[(size_t)(r2.y & 0xffffu) * 16];
        float z5 = zcol[(size_t)(r2.w & 0xffffu) * 16];
        float z6 = zcol[(size_t)(r3.y & 0xffffu) * 16];
        float z7 = zcol[(size_t)(r3.w & 0xffffu) * 16];

        // A: 8 weights (overlaps B-load latency; no barrier anywhere)
        float u0 = g1m - bits_hi_f(r0.y), u1 = g1m - bits_hi_f(r0.w);
        float u2 = g1m - bits_hi_f(r1.y), u3 = g1m - bits_hi_f(r1.w);
        float u4 = g1m - bits_hi_f(r2.y), u5 = g1m - bits_hi_f(r2.w);
        float u6 = g1m - bits_hi_f(r3.y), u7 = g1m - bits_hi_f(r3.w);
        float w0 = __expf(fmaf(q1 * u0, u0, bits_f(r0.x)));
        float w1 = __expf(fmaf(q1 * u1, u1, bits_f(r0.z)));
        float w2 = __expf(fmaf(q1 * u2, u2, bits_f(r1.x)));
        float w3 = __expf(fmaf(q1 * u3, u3, bits_f(r1.z)));
        float w4 = __expf(fmaf(q1 * u4, u4, bits_f(r2.x)));
        float w5 = __expf(fmaf(q1 * u5, u5, bits_f(r2.z)));
        float w6 = __expf(fmaf(q1 * u6, u6, bits_f(r3.x)));
        float w7 = __expf(fmaf(q1 * u7, u7, bits_f(r3.z)));

        union { uint32_t u[4]; short8 s; } af, bf;
        af.u[0] = pack_bf2(w0, w1); af.u[1] = pack_bf2(w2, w3);
        af.u[2] = pack_bf2(w4, w5); af.u[3] = pack_bf2(w6, w7);
        bf.u[0] = pack_bf2(z0, z1); bf.u[1] = pack_bf2(z2, z3);
        bf.u[2] = pack_bf2(z4, z5); bf.u[3] = pack_bf2(z6, z7);

        acc = __builtin_amdgcn_mfma_f32_16x16x32_bf16(af.s, bf.s, acc, 0, 0, 0);
    }

    // ---- reduce wave pairs (w, w+4): same M-tile, disjoint K ----
    __syncthreads();                     // records dead; redv aliases them
    if (w >= 4) redv[(w - 4) * 64 + lane] = acc;
    __syncthreads();
    if (w < 4) {
        acc += redv[mt * 64 + lane];
        // D layout (m89): D[m = q*4 + r][n = dn]
        size_t base = ((size_t)b * M_GRID + gtile * 64 + mt * 16 + q * 4) * 16 + dn;
#pragma unroll
        for (int r = 0; r < 4; ++r)
            outz[base + (size_t)r * 16] = acc[r];
    }
}

extern "C" void kernel_launch(void* const* d_in, const int* in_sizes, int n_in,
                              void* d_out, int out_size, void* d_ws, size_t ws_size,
                              hipStream_t stream) {
    // inputs (all fp32): x [8,4096,2], z [8,4096,16], lengthscale_param [2],
    // grid [64,64,2]. output: x_grid (65536 f32) ++ z_grid (524288 f32).
    const float2* x2    = (const float2*)d_in[0];
    const float*  zf    = (const float*)d_in[1];
    const float*  lsp   = (const float*)d_in[2];
    const float2* grid2 = (const float2*)d_in[3];
    float* out = (float*)d_out;

    hipLaunchKernelGGL(setconv_kernel, dim3(64, 8), dim3(512), 0, stream,
                       x2, zf, lsp, grid2, (float2*)out, out + 65536);
}

// Round 12
// 83.414 us; speedup vs baseline: 1.0790x; 1.0790x over previous
//
#include <hip/hip_runtime.h>
#include <hip/hip_bf16.h>
#include <cstdint>

// m=8, n=4096, dx=2, dz=16, grid 64x64 -> M=4096. All I/O fp32.
// R12 = R8 barrier-free MFMA K-loop + software pipeline + slimmer group:
//  - records: ex float2[4096] = (e0L = log2e*q0*(g0-x0)^2 fp32, x1 fp32),
//    nn ushort[4096] = n*16 (pre-shifted z row offset). fp32 x1 restores
//    R7-level accuracy (R11's bf16 x1 tripled absmax).
//  - K-loop: 1-ahead prefetch (next records via LDS + next z loads issued
//    after current group's weights) -> serial chain latency overlapped.
//  - z addressing: wave-uniform base + 32-bit element index (saddr form).
//  - exp2f with log2e folded into q0/q1 (saves a mul per exp).
//  - anti-correlated gtile swizzle: block (g,b>=4) handles row (g+32)&63 so
//    the two co-resident blocks of a CU get one heavy + one light row.
#define N_PTS   4096
#define M_GRID  4096
#define LOG2E   1.4426950408889634f
#define SKIP_E0L (-28.853900817779268f)   // -20 * log2(e); exp(-20)=2e-9

typedef __attribute__((ext_vector_type(8))) short  short8;   // 8 bf16
typedef __attribute__((ext_vector_type(4))) float  floatx4;

// LDS: ex float2[4096] @0 (32768 B); nn ushort[4096] @32768 (8192 B);
//      cnt @40960; red (post-loop) aliases ex.
#define OFF_EX   0
#define OFF_NN   32768
#define OFF_CNT  40960
#define SMEM_BYTES 40964

__device__ __forceinline__ uint32_t pack_bf2(float a, float b) {
    union { __hip_bfloat162 h; uint32_t u; } c;
    c.h = __float22bfloat162_rn(make_float2(a, b));
    return c.u;
}

__global__ __launch_bounds__(512, 4)
void setconv_kernel(const float2* __restrict__ x2,     // [8*4096]
                    const float*  __restrict__ zf,     // [8*4096*16]
                    const float*  __restrict__ lsp,    // [2]
                    const float2* __restrict__ grid2,  // [4096]
                    float2*       __restrict__ outx,   // x_grid [8*4096]
                    float*        __restrict__ outz)   // z_grid [8*4096*16]
{
    __shared__ __align__(16) char smem[SMEM_BYTES];
    float2*  ex   = reinterpret_cast<float2*>(smem + OFF_EX);
    ushort*  nn   = reinterpret_cast<ushort*>(smem + OFF_NN);
    int*     cntp = reinterpret_cast<int*>(smem + OFF_CNT);
    floatx4* redv = reinterpret_cast<floatx4*>(smem);   // aliases ex (late)

    const int tid  = threadIdx.x;
    const int lane = tid & 63;
    const int w    = tid >> 6;          // wave 0..7
    const int mt   = w & 3;             // M-tile (grid cols mt*16..+15)
    const int ks   = w >> 2;            // K-slab half (0/1)
    const int q    = lane >> 4;         // quarter within wave
    const int dn   = lane & 15;         // dz index (B) == m within tile (A/D)
    const int b    = blockIdx.y;        // 0..7
    // anti-correlated swizzle: co-resident blocks (i, i+256) share a CU and
    // have (b, b+4) -> give them complementary grid rows.
    const int gtile = (int)((blockIdx.x + ((b & 4) ? 32u : 0u)) & 63u);

    // lengthscale = 1e-5 + softplus(param); fold -0.5/ls^2 * log2(e)
    float p0 = lsp[0], p1 = lsp[1];
    float sp0 = (p0 > 0.f) ? (p0 + log1pf(expf(-p0))) : log1pf(expf(p0));
    float sp1 = (p1 > 0.f) ? (p1 + log1pf(expf(-p1))) : log1pf(expf(p1));
    float ls0 = 1e-5f + sp0, ls1 = 1e-5f + sp1;
    const float q0L = -0.5f * LOG2E / (ls0 * ls0);  // wgt = exp2(q0L*d0^2 + q1L*d1^2)
    const float q1L = -0.5f * LOG2E / (ls1 * ls1);

    const float2 gv = grid2[gtile * 64 + lane];
    const float  g0 = gv.x;                 // block-uniform row coord
    if (w == 0) outx[(size_t)b * M_GRID + gtile * 64 + lane] = gv;
    // col coord of this lane's A/D row (m = dn within M-tile mt)
    const float g1m = grid2[gtile * 64 + mt * 16 + dn].y;

    if (tid == 0) *cntp = 0;
    __syncthreads();

    const float2* xb = x2 + b * N_PTS;

    // ---- Phase A: compact survivors ----
    for (int t = tid; t < N_PTS; t += 512) {
        float2 xv = xb[t];
        float d0 = g0 - xv.x;
        float e0 = q0L * d0 * d0;
        bool keep = (e0 >= SKIP_E0L);
        unsigned long long m = __ballot(keep);
        int base = 0;
        if (lane == 0 && m) base = atomicAdd(cntp, __popcll(m));
        base = __shfl(base, 0);
        if (keep) {
            int off = base + __popcll(m & ((1ull << lane) - 1ull));
            ex[off] = make_float2(e0, xv.y);
            nn[off] = (ushort)(t << 4);     // element offset of z row
        }
    }
    __syncthreads();
    const int C    = *cntp;
    const int Cpad = (C + 63) & ~63;
    for (int t = C + tid; t < Cpad; t += 512) {   // sentinel: wgt -> 0
        ex[t] = make_float2(-1e30f, 0.f);
        nn[t] = 0;
    }
    __syncthreads();

    const int ngroup = Cpad >> 6;           // 64 survivors per group
    const float* zb = zf + (size_t)b * (N_PTS * 16);  // wave-uniform base

    floatx4 acc = {0.f, 0.f, 0.f, 0.f};

    if (ngroup > 0) {
        const float4* e4 = reinterpret_cast<const float4*>(ex);

        float4 A, B, Cc, D; uint4 N;
        float a0, a1, a2, a3, a4, a5, a6, a7;

#define LDREC(gi, A_, B_, C_, D_, N_) do {                                  \
        int k0_ = ((gi) << 6) + (ks << 5) + (q << 3);                       \
        int h_  = k0_ >> 1;                                                 \
        A_ = e4[h_]; B_ = e4[h_ + 1]; C_ = e4[h_ + 2]; D_ = e4[h_ + 3];     \
        N_ = *reinterpret_cast<const uint4*>(nn + k0_);                     \
    } while (0)

#define LDZ(N_) do {                                                        \
        a0 = zb[(int)((N_).x & 0xffffu) + dn];                              \
        a1 = zb[(int)((N_).x >> 16)     + dn];                              \
        a2 = zb[(int)((N_).y & 0xffffu) + dn];                              \
        a3 = zb[(int)((N_).y >> 16)     + dn];                              \
        a4 = zb[(int)((N_).z & 0xffffu) + dn];                              \
        a5 = zb[(int)((N_).z >> 16)     + dn];                              \
        a6 = zb[(int)((N_).w & 0xffffu) + dn];                              \
        a7 = zb[(int)((N_).w >> 16)     + dn];                              \
    } while (0)

        LDREC(0, A, B, Cc, D, N);
        LDZ(N);

        for (int gi = 0; gi < ngroup; ++gi) {
            const int nx = (gi + 1 < ngroup) ? gi + 1 : gi;
            float4 A2, B2, C2, D2; uint4 N2;
            LDREC(nx, A2, B2, C2, D2, N2);      // LDS issue (next group)

            // weights for current group (covers LDS latency)
            float u0 = g1m - A.y,  u1 = g1m - A.w;
            float u2 = g1m - B.y,  u3 = g1m - B.w;
            float u4 = g1m - Cc.y, u5 = g1m - Cc.w;
            float u6 = g1m - D.y,  u7 = g1m - D.w;
            float w0 = exp2f(fmaf(q1L * u0, u0, A.x));
            float w1 = exp2f(fmaf(q1L * u1, u1, A.z));
            float w2 = exp2f(fmaf(q1L * u2, u2, B.x));
            float w3 = exp2f(fmaf(q1L * u3, u3, B.z));
            float w4 = exp2f(fmaf(q1L * u4, u4, Cc.x));
            float w5 = exp2f(fmaf(q1L * u5, u5, Cc.z));
            float w6 = exp2f(fmaf(q1L * u6, u6, D.x));
            float w7 = exp2f(fmaf(q1L * u7, u7, D.z));

            union { uint32_t u[4]; short8 s; } af, bf;
            af.u[0] = pack_bf2(w0, w1); af.u[1] = pack_bf2(w2, w3);
            af.u[2] = pack_bf2(w4, w5); af.u[3] = pack_bf2(w6, w7);
            bf.u[0] = pack_bf2(a0, a1); bf.u[1] = pack_bf2(a2, a3);
            bf.u[2] = pack_bf2(a4, a5); bf.u[3] = pack_bf2(a6, a7);

            acc = __builtin_amdgcn_mfma_f32_16x16x32_bf16(af.s, bf.s, acc, 0, 0, 0);

            LDZ(N2);                            // issue next group's z loads
            A = A2; B = B2; Cc = C2; D = D2;
        }
#undef LDREC
#undef LDZ
    }

    // ---- reduce wave pairs (w, w+4): same M-tile, disjoint K ----
    __syncthreads();                     // records dead; redv aliases them
    if (w >= 4) redv[(w - 4) * 64 + lane] = acc;
    __syncthreads();
    if (w < 4) {
        acc += redv[mt * 64 + lane];
        // D layout (m89): D[m = q*4 + r][n = dn]
        size_t base = ((size_t)b * M_GRID + gtile * 64 + mt * 16 + q * 4) * 16 + dn;
#pragma unroll
        for (int r = 0; r < 4; ++r)
            outz[base + (size_t)r * 16] = acc[r];
    }
}

extern "C" void kernel_launch(void* const* d_in, const int* in_sizes, int n_in,
                              void* d_out, int out_size, void* d_ws, size_t ws_size,
                              hipStream_t stream) {
    // inputs (all fp32): x [8,4096,2], z [8,4096,16], lengthscale_param [2],
    // grid [64,64,2]. output: x_grid (65536 f32) ++ z_grid (524288 f32).
    const float2* x2    = (const float2*)d_in[0];
    const float*  zf    = (const float*)d_in[1];
    const float*  lsp   = (const float*)d_in[2];
    const float2* grid2 = (const float2*)d_in[3];
    float* out = (float*)d_out;

    hipLaunchKernelGGL(setconv_kernel, dim3(64, 8), dim3(512), 0, stream,
                       x2, zf, lsp, grid2, (float2*)out, out + 65536);
}

// Round 15
// 81.731 us; speedup vs baseline: 1.1012x; 1.0206x over previous
//
#include <hip/hip_runtime.h>
#include <hip/hip_bf16.h>
#include <cstdint>

// m=8, n=4096, dx=2, dz=16, grid 64x64 -> M=4096. All I/O fp32.
// R15 = R13's pipeline schedule, restructured source (R13/R14 both died to
// "container failed twice"; source simplified to dodge any compile-side
// pathology while keeping the experiment):
//  - rotating 3-set record pipeline: records for group gi+1 are in registers
//    a full iteration before their z loads issue; z loads for gi+1 issue at
//    the TOP of iteration gi -> a whole body (~250+ cy) of latency cover.
//  - skip threshold -14 (exp(-14)=8e-7; worst-case err ~0.014 vs 0.28
//    margin) -> ~16% fewer survivors than -20.
//  - Phase A reads x via float4 (2 points/thread/iter).
#define N_PTS   4096
#define M_GRID  4096
#define LOG2E   1.4426950408889634f
#define SKIP_E0L (-20.197730572445487f)   // -14 * log2(e)

typedef __attribute__((ext_vector_type(8))) short  short8;   // 8 bf16
typedef __attribute__((ext_vector_type(4))) float  floatx4;

// LDS: ex float2[4096] @0 (32768 B); nn ushort[4096] @32768 (8192 B);
//      cnt @40960; red (post-loop) aliases ex.
#define OFF_EX   0
#define OFF_NN   32768
#define OFF_CNT  40960
#define SMEM_BYTES 40964

__device__ __forceinline__ uint32_t pack_bf2(float a, float b) {
    union { __hip_bfloat162 h; uint32_t u; } c;
    c.h = __float22bfloat162_rn(make_float2(a, b));
    return c.u;
}

struct Rec { float4 a, b, c, d; uint4 n; };

__global__ __launch_bounds__(512, 4)
void setconv_kernel(const float2* __restrict__ x2,     // [8*4096]
                    const float*  __restrict__ zf,     // [8*4096*16]
                    const float*  __restrict__ lsp,    // [2]
                    const float2* __restrict__ grid2,  // [4096]
                    float2*       __restrict__ outx,   // x_grid [8*4096]
                    float*        __restrict__ outz)   // z_grid [8*4096*16]
{
    __shared__ __align__(16) char smem[SMEM_BYTES];
    float2*  ex   = reinterpret_cast<float2*>(smem + OFF_EX);
    ushort*  nn   = reinterpret_cast<ushort*>(smem + OFF_NN);
    int*     cntp = reinterpret_cast<int*>(smem + OFF_CNT);
    floatx4* redv = reinterpret_cast<floatx4*>(smem);   // aliases ex (late)

    const int tid  = threadIdx.x;
    const int lane = tid & 63;
    const int w    = tid >> 6;          // wave 0..7
    const int mt   = w & 3;             // M-tile (grid cols mt*16..+15)
    const int ks   = w >> 2;            // K-slab half (0/1)
    const int q    = lane >> 4;         // quarter within wave
    const int dn   = lane & 15;         // dz index (B) == m within tile (A/D)
    const int b    = blockIdx.y;        // 0..7
    // anti-correlated swizzle: co-resident blocks (i, i+256) have (b, b+4)
    // -> complementary grid rows (heavy center + light edge on one CU).
    const int gtile = (int)((blockIdx.x + ((b & 4) ? 32u : 0u)) & 63u);

    // lengthscale = 1e-5 + softplus(param); fold -0.5/ls^2 * log2(e)
    float p0 = lsp[0], p1 = lsp[1];
    float sp0 = (p0 > 0.f) ? (p0 + log1pf(expf(-p0))) : log1pf(expf(p0));
    float sp1 = (p1 > 0.f) ? (p1 + log1pf(expf(-p1))) : log1pf(expf(p1));
    float ls0 = 1e-5f + sp0, ls1 = 1e-5f + sp1;
    const float q0L = -0.5f * LOG2E / (ls0 * ls0);  // wgt = exp2(q0L*d0^2+q1L*d1^2)
    const float q1L = -0.5f * LOG2E / (ls1 * ls1);

    const float2 gv = grid2[gtile * 64 + lane];
    const float  g0 = gv.x;                 // block-uniform row coord
    if (w == 0) outx[(size_t)b * M_GRID + gtile * 64 + lane] = gv;
    // col coord of this lane's A/D row (m = dn within M-tile mt)
    const float g1m = grid2[gtile * 64 + mt * 16 + dn].y;

    if (tid == 0) *cntp = 0;
    __syncthreads();

    // ---- Phase A: compact survivors (x via float4, 2 points/iter) ----
    const float4* xb4 = reinterpret_cast<const float4*>(x2 + b * N_PTS);
    for (int tt = tid; tt < N_PTS / 2; tt += 512) {
        float4 xv = xb4[tt];
#pragma unroll
        for (int h = 0; h < 2; ++h) {
            float x0 = h ? xv.z : xv.x;
            float x1 = h ? xv.w : xv.y;
            float d0 = g0 - x0;
            float e0 = q0L * d0 * d0;
            bool keep = (e0 >= SKIP_E0L);
            unsigned long long m = __ballot(keep);
            int base = 0;
            if (lane == 0 && m) base = atomicAdd(cntp, __popcll(m));
            base = __shfl(base, 0);
            if (keep) {
                int off = base + __popcll(m & ((1ull << lane) - 1ull));
                ex[off] = make_float2(e0, x1);
                nn[off] = (ushort)((2 * tt + h) << 4);   // z row elem offset
            }
        }
    }
    __syncthreads();
    const int C    = *cntp;
    const int Cpad = (C + 63) & ~63;
    for (int t = C + tid; t < Cpad; t += 512) {   // sentinel: wgt -> 0
        ex[t] = make_float2(-1e30f, 0.f);
        nn[t] = 0;
    }
    __syncthreads();

    const int ngroup = Cpad >> 6;           // 64 survivors per group
    const float* zb = zf + (size_t)b * (N_PTS * 16);  // wave-uniform base

    floatx4 acc = {0.f, 0.f, 0.f, 0.f};

    if (ngroup > 0) {
        const float4* e4 = reinterpret_cast<const float4*>(ex);
        const int kofs = (ks << 5) + (q << 3);

        auto ldrec = [&](int gi) {
            Rec r;
            int k0 = (gi << 6) + kofs;
            int h  = k0 >> 1;
            r.a = e4[h]; r.b = e4[h + 1]; r.c = e4[h + 2]; r.d = e4[h + 3];
            r.n = *reinterpret_cast<const uint4*>(nn + k0);
            return r;
        };

        Rec rc = ldrec(0);                               // group 0 records
        Rec rn = ldrec(ngroup > 1 ? 1 : 0);              // group 1 records
        float zc[8], zn[8];
#pragma unroll
        for (int j = 0; j < 8; ++j) {
            uint32_t nv = (&rc.n.x)[j >> 1];
            zc[j] = zb[(int)((j & 1) ? (nv >> 16) : (nv & 0xffffu)) + dn];
        }

        for (int gi = 0; gi < ngroup; ++gi) {
            // 1. z loads for group gi+1 (addresses resident since gi-1)
            if (gi + 1 < ngroup) {
#pragma unroll
                for (int j = 0; j < 8; ++j) {
                    uint32_t nv = (&rn.n.x)[j >> 1];
                    zn[j] = zb[(int)((j & 1) ? (nv >> 16) : (nv & 0xffffu)) + dn];
                }
            }
            // 2. records for group gi+2 (LDS; consumed next iteration)
            Rec r2 = ldrec(gi + 2 < ngroup ? gi + 2 : ngroup - 1);

            // 3. weights + MFMA for group gi (covers 1+2 latency)
            float u0 = g1m - rc.a.y, u1 = g1m - rc.a.w;
            float u2 = g1m - rc.b.y, u3 = g1m - rc.b.w;
            float u4 = g1m - rc.c.y, u5 = g1m - rc.c.w;
            float u6 = g1m - rc.d.y, u7 = g1m - rc.d.w;
            float w0 = exp2f(fmaf(q1L * u0, u0, rc.a.x));
            float w1 = exp2f(fmaf(q1L * u1, u1, rc.a.z));
            float w2 = exp2f(fmaf(q1L * u2, u2, rc.b.x));
            float w3 = exp2f(fmaf(q1L * u3, u3, rc.b.z));
            float w4 = exp2f(fmaf(q1L * u4, u4, rc.c.x));
            float w5 = exp2f(fmaf(q1L * u5, u5, rc.c.z));
            float w6 = exp2f(fmaf(q1L * u6, u6, rc.d.x));
            float w7 = exp2f(fmaf(q1L * u7, u7, rc.d.z));

            union { uint32_t u[4]; short8 s; } af, bf;
            af.u[0] = pack_bf2(w0, w1);     af.u[1] = pack_bf2(w2, w3);
            af.u[2] = pack_bf2(w4, w5);     af.u[3] = pack_bf2(w6, w7);
            bf.u[0] = pack_bf2(zc[0], zc[1]); bf.u[1] = pack_bf2(zc[2], zc[3]);
            bf.u[2] = pack_bf2(zc[4], zc[5]); bf.u[3] = pack_bf2(zc[6], zc[7]);

            acc = __builtin_amdgcn_mfma_f32_16x16x32_bf16(af.s, bf.s, acc, 0, 0, 0);

            // 4. rotate
            rc = rn; rn = r2;
#pragma unroll
            for (int j = 0; j < 8; ++j) zc[j] = zn[j];
        }
    }

    // ---- reduce wave pairs (w, w+4): same M-tile, disjoint K ----
    __syncthreads();                     // records dead; redv aliases them
    if (w >= 4) redv[(w - 4) * 64 + lane] = acc;
    __syncthreads();
    if (w < 4) {
        acc += redv[mt * 64 + lane];
        // D layout (m89): D[m = q*4 + r][n = dn]
        size_t base = ((size_t)b * M_GRID + gtile * 64 + mt * 16 + q * 4) * 16 + dn;
#pragma unroll
        for (int r = 0; r < 4; ++r)
            outz[base + (size_t)r * 16] = acc[r];
    }
}

extern "C" void kernel_launch(void* const* d_in, const int* in_sizes, int n_in,
                              void* d_out, int out_size, void* d_ws, size_t ws_size,
                              hipStream_t stream) {
    // inputs (all fp32): x [8,4096,2], z [8,4096,16], lengthscale_param [2],
    // grid [64,64,2]. output: x_grid (65536 f32) ++ z_grid (524288 f32).
    const float2* x2    = (const float2*)d_in[0];
    const float*  zf    = (const float*)d_in[1];
    const float*  lsp   = (const float*)d_in[2];
    const float2* grid2 = (const float2*)d_in[3];
    float* out = (float*)d_out;

    hipLaunchKernelGGL(setconv_kernel, dim3(64, 8), dim3(512), 0, stream,
                       x2, zf, lsp, grid2, (float2*)out, out + 65536);
}